// Round 1
// baseline (420.450 us; speedup 1.0000x reference)
//
#include <hip/hip_runtime.h>
#include <math.h>

// Problem constants
#define B  4
#define S  2048
#define H  1024
#define D  64
#define ROWS (B*S)      // 8192

// Workspace layout (float offsets)
#define WS_Q     0
#define WS_K     (WS_Q + ROWS*D)
#define WS_V     (WS_K + ROWS*D)
#define WS_HEAD  (WS_V + ROWS*D)          // accumulated (unnormalized) head
#define WS_SUMW  (WS_HEAD + ROWS*D)       // softmax denominators
#define WS_MU    (WS_SUMW + ROWS)
#define WS_INV   (WS_MU + ROWS)           // 1/(sigma+eps)
#define WS_KSUM  (WS_INV + ROWS)          // [B][D]
#define WS_M     (WS_KSUM + B*D)          // [B][D][D]  K^T K per batch
#define WS_WEFF  (WS_M + B*D*D)           // [D][H]  sum of Wout blocks
#define WS_END   (WS_WEFF + D*H)          // ~2.2M floats = 8.9 MB

// ---------------------------------------------------------------------------
// 0) zero the accumulated regions (harness poisons ws with 0xAA every call)
__global__ void zero_ws(float* __restrict__ ws) {
    int i = blockIdx.x * 256 + threadIdx.x;
    const int n1 = ROWS*D + ROWS;        // head + sumw (contiguous)
    const int n2 = B*D + B*D*D;          // ksum + M (contiguous)
    if (i < n1) ws[WS_HEAD + i] = 0.0f;
    else {
        i -= n1;
        if (i < n2) ws[WS_KSUM + i] = 0.0f;
    }
}

// ---------------------------------------------------------------------------
// 1) q/k/v = X @ W + b.   grid (ROWS/64, 3), block 256.
//    64x64 output tile per block, K-loop in steps of 32.
__global__ __launch_bounds__(256) void qkv_gemm(
    const float* __restrict__ query, const float* __restrict__ key,
    const float* __restrict__ value,
    const float* __restrict__ Wq, const float* __restrict__ Wk,
    const float* __restrict__ Wv,
    const float* __restrict__ bq, const float* __restrict__ bk,
    const float* __restrict__ bvp, float* __restrict__ ws)
{
    const int mat = blockIdx.y;
    const float* X    = (mat == 0) ? query : (mat == 1) ? key : value;
    const float* W    = (mat == 0) ? Wq    : (mat == 1) ? Wk  : Wv;
    const float* bias = (mat == 0) ? bq    : (mat == 1) ? bk  : bvp;
    float* OUT = ws + ((mat == 0) ? WS_Q : (mat == 1) ? WS_K : WS_V);

    const int r0 = blockIdx.x * 64;
    __shared__ float xT[32][68];   // [k][row], pad 68: conflict-free col reads
    __shared__ float wt[32][64];   // [k][col]

    const int t  = threadIdx.x;
    const int tr = t >> 4;         // 0..15 -> rows tr*4..tr*4+3
    const int tc = t & 15;         // 0..15 -> cols tc*4..tc*4+3

    float acc[4][4] = {};

    for (int kc = 0; kc < H; kc += 32) {
        #pragma unroll
        for (int u = 0; u < 2; ++u) {
            int li = t + u * 256;              // 0..511
            int r  = li >> 3;                  // 0..63
            int c4 = li & 7;                   // 0..7
            float4 xv = *(const float4*)&X[(size_t)(r0 + r) * H + kc + c4 * 4];
            xT[c4*4+0][r] = xv.x; xT[c4*4+1][r] = xv.y;
            xT[c4*4+2][r] = xv.z; xT[c4*4+3][r] = xv.w;
            int kk  = li >> 4;                 // 0..31
            int wc4 = li & 15;                 // 0..15
            *(float4*)&wt[kk][wc4*4] = *(const float4*)&W[(size_t)(kc + kk) * D + wc4 * 4];
        }
        __syncthreads();
        #pragma unroll
        for (int kk = 0; kk < 32; ++kk) {
            float4 a = *(const float4*)&xT[kk][tr*4];
            float4 b = *(const float4*)&wt[kk][tc*4];
            float av[4] = {a.x, a.y, a.z, a.w};
            float bw[4] = {b.x, b.y, b.z, b.w};
            #pragma unroll
            for (int i = 0; i < 4; ++i)
                #pragma unroll
                for (int j = 0; j < 4; ++j)
                    acc[i][j] += av[i] * bw[j];
        }
        __syncthreads();
    }

    #pragma unroll
    for (int i = 0; i < 4; ++i) {
        float4 o;
        o.x = acc[i][0] + bias[tc*4+0];
        o.y = acc[i][1] + bias[tc*4+1];
        o.z = acc[i][2] + bias[tc*4+2];
        o.w = acc[i][3] + bias[tc*4+3];
        *(float4*)&OUT[(size_t)(r0 + tr*4 + i) * D + tc*4] = o;
    }
}

// ---------------------------------------------------------------------------
// 2) Weff[d][n] = sum_h Wout[h*64+d][n].   grid 256, block 256.
__global__ void weff_kernel(const float* __restrict__ Wout, float* __restrict__ ws) {
    int idx = blockIdx.x * 256 + threadIdx.x;   // < D*H
    int d = idx >> 10, n = idx & 1023;
    float s = 0.0f;
    #pragma unroll
    for (int h = 0; h < 16; ++h) s += Wout[(size_t)(h * 64 + d) * H + n];
    ws[WS_WEFF + idx] = s;
}

// ---------------------------------------------------------------------------
// 3) per-batch K column sums and M = K^T K.  grid B*32, block 256.
//    Each block handles 64 rows of one batch; atomicAdd partials.
__global__ __launch_bounds__(256) void kstats(float* __restrict__ ws) {
    const int b     = blockIdx.x >> 5;
    const int chunk = blockIdx.x & 31;
    const float* Kp = ws + WS_K + (size_t)b * S * D;
    const int j0 = chunk * 64;

    __shared__ float kt[64][64];
    const int t = threadIdx.x;
    #pragma unroll
    for (int u = 0; u < 4; ++u) {
        int li = t + u * 256;          // 0..1023
        int j = li >> 4, c4 = li & 15;
        *(float4*)&kt[j][c4*4] = *(const float4*)&Kp[(size_t)(j0 + j) * D + c4 * 4];
    }
    __syncthreads();

    const int td = t >> 4, te = t & 15;
    float acc[4][4] = {};
    for (int j = 0; j < 64; ++j) {
        float4 a  = *(const float4*)&kt[j][td*4];
        float4 bb = *(const float4*)&kt[j][te*4];
        float av[4] = {a.x, a.y, a.z, a.w};
        float bw[4] = {bb.x, bb.y, bb.z, bb.w};
        #pragma unroll
        for (int i = 0; i < 4; ++i)
            #pragma unroll
            for (int l = 0; l < 4; ++l)
                acc[i][l] += av[i] * bw[l];
    }
    float* M = ws + WS_M + (size_t)b * D * D;
    #pragma unroll
    for (int i = 0; i < 4; ++i)
        #pragma unroll
        for (int l = 0; l < 4; ++l)
            atomicAdd(&M[(td*4 + i) * D + te*4 + l], acc[i][l]);

    if (t < 64) {
        float s = 0.0f;
        for (int j = 0; j < 64; ++j) s += kt[j][t];
        atomicAdd(&ws[WS_KSUM + b * D + t], s);
    }
}

// ---------------------------------------------------------------------------
// 4) per-row mean / 1/(sigma+eps):
//    sum   = (q . ksum)/32 ;  sumsq = (q^T M q)/1024
//    grid ROWS/4, block 256 (one wave64 per row).
__global__ __launch_bounds__(256) void rowstats(float* __restrict__ ws) {
    const int wave = threadIdx.x >> 6, lane = threadIdx.x & 63;
    const int row = blockIdx.x * 4 + wave;
    const int b = row >> 11;                 // row / 2048
    const float qv = ws[WS_Q + (size_t)row * D + lane];
    const float* M = ws + WS_M + (size_t)b * D * D;

    float y = 0.0f;
    #pragma unroll 8
    for (int d2 = 0; d2 < 64; ++d2)
        y += __shfl(qv, d2, 64) * M[d2 * D + lane];

    float z  = y * qv;                             // partial q^T M q
    float sv = qv * ws[WS_KSUM + b * D + lane];    // partial q . ksum
    #pragma unroll
    for (int m = 32; m > 0; m >>= 1) {
        z  += __shfl_xor(z,  m, 64);
        sv += __shfl_xor(sv, m, 64);
    }
    if (lane == 0) {
        float sum   = sv * (1.0f / 32.0f);
        float sumsq = z  * (1.0f / 1024.0f);
        float mu  = sum * (1.0f / 2048.0f);
        float var = (sumsq - sum * sum * (1.0f / 2048.0f)) * (1.0f / 2047.0f);
        var = fmaxf(var, 0.0f);
        ws[WS_MU  + row] = mu;
        ws[WS_INV + row] = 1.0f / (sqrtf(var) + 1e-8f);
    }
}

// ---------------------------------------------------------------------------
// 5) flash-style pass: head_unnorm += sum_j exp((s-mu)*inv) * v_j ; sumw += ...
//    grid (ROWS/32, 4 k-splits), block 256.
#define QT 32
#define KT 32
#define KSPLIT 4
__global__ __launch_bounds__(256) void attention(float* __restrict__ ws) {
    const int r0 = blockIdx.x * QT;
    const int b  = r0 >> 11;
    const int jbase = blockIdx.y * (S / KSPLIT);
    const float* Kp = ws + WS_K + (size_t)b * S * D;
    const float* Vp = ws + WS_V + (size_t)b * S * D;

    __shared__ float qs[QT][68];     // pre-scaled by inv/32; pad 68
    __shared__ float cs[QT];         // -mu*inv
    __shared__ float kst[KT][68];    // pad 68
    __shared__ float vst[KT][64];
    __shared__ float wsm[QT][33];    // pad 33

    const int t = threadIdx.x;
    // stage q (scaled)
    #pragma unroll
    for (int u = 0; u < 2; ++u) {
        int li = t + u * 256;
        int qi = li >> 4, c4 = li & 15;
        float a = ws[WS_INV + r0 + qi] * (1.0f / 32.0f);
        float4 qv = *(const float4*)&ws[WS_Q + (size_t)(r0 + qi) * D + c4 * 4];
        qv.x *= a; qv.y *= a; qv.z *= a; qv.w *= a;
        *(float4*)&qs[qi][c4*4] = qv;
    }
    if (t < QT) cs[t] = -ws[WS_MU + r0 + t] * ws[WS_INV + r0 + t];

    const int qi  = t >> 3;   // 0..31
    const int seg = t & 7;    // 0..7
    float oacc[8] = {};
    float swsum = 0.0f;

    for (int kt0 = 0; kt0 < S / KSPLIT; kt0 += KT) {
        const int j0 = jbase + kt0;
        __syncthreads();   // protect prior reads of kst/vst/wsm (also covers q staging)
        #pragma unroll
        for (int u = 0; u < 2; ++u) {
            int li = t + u * 256;
            int j = li >> 4, c4 = li & 15;
            *(float4*)&kst[j][c4*4] = *(const float4*)&Kp[(size_t)(j0 + j) * D + c4 * 4];
            *(float4*)&vst[j][c4*4] = *(const float4*)&Vp[(size_t)(j0 + j) * D + c4 * 4];
        }
        __syncthreads();

        // scores: thread handles keys kj = seg + 8*kk (bank-friendly)
        float sc[4] = {};
        #pragma unroll
        for (int d4 = 0; d4 < 16; ++d4) {
            float4 qf = *(const float4*)&qs[qi][d4*4];
            #pragma unroll
            for (int kk = 0; kk < 4; ++kk) {
                float4 kf = *(const float4*)&kst[seg + 8*kk][d4*4];
                sc[kk] += qf.x*kf.x + qf.y*kf.y + qf.z*kf.z + qf.w*kf.w;
            }
        }
        const float c = cs[qi];
        #pragma unroll
        for (int kk = 0; kk < 4; ++kk) {
            float w = __expf(sc[kk] + c);
            wsm[qi][seg + 8*kk] = w;
            swsum += w;
        }
        __syncthreads();

        // o update: thread handles dims seg*8..seg*8+7 of row qi
        #pragma unroll 8
        for (int kj = 0; kj < KT; ++kj) {
            float w = wsm[qi][kj];
            float4 v0 = *(const float4*)&vst[kj][seg*8];
            float4 v1 = *(const float4*)&vst[kj][seg*8 + 4];
            oacc[0] += w * v0.x; oacc[1] += w * v0.y;
            oacc[2] += w * v0.z; oacc[3] += w * v0.w;
            oacc[4] += w * v1.x; oacc[5] += w * v1.y;
            oacc[6] += w * v1.z; oacc[7] += w * v1.w;
        }
    }

    #pragma unroll
    for (int u = 0; u < 8; ++u)
        atomicAdd(&ws[WS_HEAD + (size_t)(r0 + qi) * D + seg*8 + u], oacc[u]);
    atomicAdd(&ws[WS_SUMW + r0 + qi], swsum);
}

// ---------------------------------------------------------------------------
// 6) out = (head/sumw) @ Weff + bout.   grid (ROWS/8, H/256), block 256.
__global__ __launch_bounds__(256) void finalize(
    const float* __restrict__ bout, const float* __restrict__ wsc,
    float* __restrict__ out)
{
    const int r0 = blockIdx.x * 8;
    const int c0 = blockIdx.y * 256;
    const int t  = threadIdx.x;
    __shared__ float hs[8][64];
    if (t < 128) {
        int r = t >> 4, c4 = t & 15;
        float inv = 1.0f / wsc[WS_SUMW + r0 + r];
        float4 h = *(const float4*)&wsc[WS_HEAD + (size_t)(r0 + r) * D + c4 * 4];
        h.x *= inv; h.y *= inv; h.z *= inv; h.w *= inv;
        *(float4*)&hs[r][c4*4] = h;
    }
    __syncthreads();

    const float* Wf = wsc + WS_WEFF;
    float acc[8] = {};
    #pragma unroll 4
    for (int d4 = 0; d4 < 16; ++d4) {
        float w0 = Wf[(size_t)(d4*4 + 0) * H + c0 + t];
        float w1 = Wf[(size_t)(d4*4 + 1) * H + c0 + t];
        float w2 = Wf[(size_t)(d4*4 + 2) * H + c0 + t];
        float w3 = Wf[(size_t)(d4*4 + 3) * H + c0 + t];
        #pragma unroll
        for (int r = 0; r < 8; ++r) {
            float4 h = *(const float4*)&hs[r][d4*4];
            acc[r] += h.x*w0 + h.y*w1 + h.z*w2 + h.w*w3;
        }
    }
    float bb = bout[c0 + t];
    #pragma unroll
    for (int r = 0; r < 8; ++r)
        out[(size_t)(r0 + r) * H + c0 + t] = acc[r] + bb;
}

// ---------------------------------------------------------------------------
extern "C" void kernel_launch(void* const* d_in, const int* in_sizes, int n_in,
                              void* d_out, int out_size, void* d_ws, size_t ws_size,
                              hipStream_t stream) {
    const float* query = (const float*)d_in[0];
    const float* key   = (const float*)d_in[1];
    const float* value = (const float*)d_in[2];
    // d_in[3] = mask: adding -1e-32 is a no-op in fp32 -> never read.
    const float* Wq   = (const float*)d_in[4];
    const float* bq   = (const float*)d_in[5];
    const float* Wk   = (const float*)d_in[6];
    const float* bk   = (const float*)d_in[7];
    const float* Wv   = (const float*)d_in[8];
    const float* bv   = (const float*)d_in[9];
    const float* Wout = (const float*)d_in[10];
    const float* bout = (const float*)d_in[11];
    // d_in[12] = seq_mask: even when set, the tri mask adds -1e-32 (no-op) -> never read.

    float* ws  = (float*)d_ws;    // needs WS_END*4 ~= 8.9 MB
    float* out = (float*)d_out;

    const int nz = (ROWS*D + ROWS) + (B*D + B*D*D);
    zero_ws<<<(nz + 255) / 256, 256, 0, stream>>>(ws);
    qkv_gemm<<<dim3(ROWS/64, 3), 256, 0, stream>>>(query, key, value,
                                                   Wq, Wk, Wv, bq, bk, bv, ws);
    weff_kernel<<<(D*H)/256, 256, 0, stream>>>(Wout, ws);
    kstats<<<B*32, 256, 0, stream>>>(ws);
    rowstats<<<ROWS/4, 256, 0, stream>>>(ws);
    attention<<<dim3(ROWS/QT, KSPLIT), 256, 0, stream>>>(ws);
    finalize<<<dim3(ROWS/8, H/256), 256, 0, stream>>>(bout, ws, out);
}

// Round 2
// 263.621 us; speedup vs baseline: 1.5949x; 1.5949x over previous
//
#include <hip/hip_runtime.h>
#include <math.h>

// Problem constants
#define B_  4
#define S_  2048
#define H_  1024
#define D_  64
#define ROWS (B_*S_)      // 8192

typedef __attribute__((ext_vector_type(4))) float  floatx4;
typedef __attribute__((ext_vector_type(8))) short  short8;
typedef __attribute__((ext_vector_type(8))) __bf16 bf16x8;

// ---- workspace layout ----
// float region (offsets in floats):
#define WS_HEAD  0                        // ROWS*D fp32 accum (atomic)
#define WS_SUMW  (WS_HEAD + ROWS*D_)      // ROWS
#define WS_KSUM  (WS_SUMW + ROWS)         // B*D
#define WS_M     (WS_KSUM + B_*D_)        // B*D*D  (K^T K per batch)
#define WS_A2    (WS_M + B_*D_*D_)        // ROWS   inv/32
#define WS_C2    (WS_A2 + ROWS)           // ROWS   -mu*inv
#define WS_WEFF  (WS_C2 + ROWS)           // D*H
#define WS_FEND  (WS_WEFF + D_*H_)        // 631040 floats
// bf16(short) region, starts right after the float region:
#define WB_QB 0                           // [ROWS][64] row-major
#define WB_KB (WB_QB + ROWS*D_)           // [ROWS][64] row-major
#define WB_VT (WB_KB + ROWS*D_)           // [B][64][2048]  V transposed
#define WB_WT (WB_VT + ROWS*D_)           // [3][64][1024]  W transposed bf16
#define WB_END (WB_WT + 3*D_*H_)
// zeroed range: HEAD+SUMW+KSUM+M contiguous
#define NZERO (ROWS*D_ + ROWS + B_*D_ + B_*D_*D_)

__device__ __forceinline__ unsigned short f2bf(float f) {
    union { float f; unsigned u; } v; v.f = f;
    unsigned r = v.u + 0x7FFFu + ((v.u >> 16) & 1u);   // RNE
    return (unsigned short)(r >> 16);
}
__device__ __forceinline__ float bf2f(short s) {
    union { unsigned u; float f; } v;
    v.u = ((unsigned)(unsigned short)s) << 16; return v.f;
}
__device__ __forceinline__ bf16x8 ldb(const short* p) {
    union { short8 s; bf16x8 b; } u; u.s = *(const short8*)p; return u.b;
}
#define MFMA(a,b,c) __builtin_amdgcn_mfma_f32_16x16x32_bf16(a, b, c, 0, 0, 0)
// per-wave LDS ordering fence: lgkmcnt(0) only, vmcnt stays in flight
__device__ __forceinline__ void lds_fence() {
    __builtin_amdgcn_wave_barrier();
    __builtin_amdgcn_s_waitcnt(0xc07f);
    __builtin_amdgcn_wave_barrier();
}

// ---------------------------------------------------------------------------
// 0) zero the accumulated fp32 regions
__global__ void zero_ws(float* __restrict__ wsf) {
    int i = blockIdx.x * 256 + threadIdx.x;
    if (i < NZERO) wsf[i] = 0.0f;
}

// ---------------------------------------------------------------------------
// 1) prep: Weff = sum_h Wout block rows (fp32); WT = bf16 transposed Wq/Wk/Wv
__global__ void prep(const float* __restrict__ Wq, const float* __restrict__ Wk,
                     const float* __restrict__ Wv, const float* __restrict__ Wout,
                     float* __restrict__ wsf) {
    int idx = blockIdx.x * 256 + threadIdx.x;
    if (idx < D_*H_) {
        int d = idx >> 10, n = idx & 1023;
        float s = 0.0f;
        #pragma unroll
        for (int h = 0; h < 16; ++h) s += Wout[(size_t)(h * 64 + d) * H_ + n];
        wsf[WS_WEFF + idx] = s;
    } else {
        int i2 = idx - D_*H_;                  // < 3*64*1024
        int mat = i2 >> 16, rem = i2 & 65535;
        int n = rem >> 10, k = rem & 1023;
        const float* W = (mat == 0) ? Wq : (mat == 1) ? Wk : Wv;
        short* wsb = (short*)(wsf + WS_FEND);
        wsb[WB_WT + i2] = (short)f2bf(W[(size_t)k * D_ + n]);
    }
}

// ---------------------------------------------------------------------------
// 2) q/k/v = bf16(X @ W + b) via MFMA.  grid (ROWS/64, 3), block 256.
//    Wave w handles 16 rows; 4 n-tiles; K=1024 in steps of 32.
__global__ __launch_bounds__(256) void qkv_mfma(
    const float* __restrict__ query, const float* __restrict__ key,
    const float* __restrict__ value,
    const float* __restrict__ bq, const float* __restrict__ bk,
    const float* __restrict__ bvp, float* __restrict__ wsf)
{
    short* wsb = (short*)(wsf + WS_FEND);
    const int mat = blockIdx.y;
    const float* X    = (mat == 0) ? query : (mat == 1) ? key : value;
    const float* bias = (mat == 0) ? bq    : (mat == 1) ? bk  : bvp;
    const short* WT = wsb + WB_WT + mat * (D_*H_);

    const int t = threadIdx.x, w = t >> 6, lane = t & 63;
    const int l15 = lane & 15, g = lane >> 4;
    const int row = blockIdx.x * 64 + w * 16 + l15;      // A-frag row (m)
    const float* Xrow = X + (size_t)row * H_;

    floatx4 acc[4] = {};
    for (int k = 0; k < H_; k += 32) {
        float4 a0 = *(const float4*)&Xrow[k + g*8];
        float4 a1 = *(const float4*)&Xrow[k + g*8 + 4];
        union { short8 s; bf16x8 b; } uf;
        uf.s[0]=(short)f2bf(a0.x); uf.s[1]=(short)f2bf(a0.y);
        uf.s[2]=(short)f2bf(a0.z); uf.s[3]=(short)f2bf(a0.w);
        uf.s[4]=(short)f2bf(a1.x); uf.s[5]=(short)f2bf(a1.y);
        uf.s[6]=(short)f2bf(a1.z); uf.s[7]=(short)f2bf(a1.w);
        #pragma unroll
        for (int nt = 0; nt < 4; ++nt) {
            bf16x8 bf = ldb(&WT[(size_t)(nt*16 + l15) * H_ + k + g*8]);
            acc[nt] = MFMA(uf.b, bf, acc[nt]);
        }
    }

    if (mat < 2) {
        short* OUT = wsb + ((mat == 0) ? WB_QB : WB_KB);
        #pragma unroll
        for (int nt = 0; nt < 4; ++nt) {
            int n = nt*16 + l15;
            float bb = bias[n];
            #pragma unroll
            for (int r = 0; r < 4; ++r) {
                int rr = blockIdx.x * 64 + w * 16 + 4*g + r;
                OUT[(size_t)rr * D_ + n] = (short)f2bf(acc[nt][r] + bb);
            }
        }
    } else {
        short* VT = wsb + WB_VT;
        int b  = (blockIdx.x * 64) >> 11;
        int s0 = (blockIdx.x * 64 + w * 16 + 4*g) & (S_ - 1);
        #pragma unroll
        for (int nt = 0; nt < 4; ++nt) {
            int d = nt*16 + l15;
            float bb = bias[d];
            short4 pk;
            pk.x = (short)f2bf(acc[nt][0] + bb); pk.y = (short)f2bf(acc[nt][1] + bb);
            pk.z = (short)f2bf(acc[nt][2] + bb); pk.w = (short)f2bf(acc[nt][3] + bb);
            *(short4*)&VT[((size_t)b * D_ + d) * S_ + s0] = pk;
        }
    }
}

// ---------------------------------------------------------------------------
// 3) per-batch K column sums and M = K^T K (fp32 from bf16 K).
__global__ __launch_bounds__(256) void kstats(float* __restrict__ wsf) {
    const short* Kb = (short*)(wsf + WS_FEND) + WB_KB;
    const int b     = blockIdx.x >> 5;
    const int chunk = blockIdx.x & 31;
    const size_t base = ((size_t)b * S_ + chunk * 64) * D_;

    __shared__ float kt[64][64];
    const int t = threadIdx.x;
    #pragma unroll
    for (int u = 0; u < 2; ++u) {
        int c = t + u * 256;              // 0..511 chunks of 8
        int j = c >> 3, c8 = c & 7;
        short8 kv = *(const short8*)&Kb[base + (size_t)j * D_ + c8 * 8];
        #pragma unroll
        for (int i = 0; i < 8; ++i) kt[j][c8*8 + i] = bf2f(kv[i]);
    }
    __syncthreads();

    const int td = t >> 4, te = t & 15;
    float acc[4][4] = {};
    for (int j = 0; j < 64; ++j) {
        float4 a  = *(const float4*)&kt[j][td*4];
        float4 bb = *(const float4*)&kt[j][te*4];
        float av[4] = {a.x, a.y, a.z, a.w};
        float bw[4] = {bb.x, bb.y, bb.z, bb.w};
        #pragma unroll
        for (int i = 0; i < 4; ++i)
            #pragma unroll
            for (int l = 0; l < 4; ++l)
                acc[i][l] += av[i] * bw[l];
    }
    float* M = wsf + WS_M + (size_t)b * D_ * D_;
    #pragma unroll
    for (int i = 0; i < 4; ++i)
        #pragma unroll
        for (int l = 0; l < 4; ++l)
            atomicAdd(&M[(td*4 + i) * D_ + te*4 + l], acc[i][l]);

    if (t < 64) {
        float s = 0.0f;
        for (int j = 0; j < 64; ++j) s += kt[j][t];
        atomicAdd(&wsf[WS_KSUM + b * D_ + t], s);
    }
}

// ---------------------------------------------------------------------------
// 4) row stats -> a2 = inv/32, c2 = -mu*inv.  8 rows/wave (M-row reuse).
//    grid ROWS/32, block 256.
__global__ __launch_bounds__(256) void rowstats(float* __restrict__ wsf) {
    const short* Qb = (short*)(wsf + WS_FEND) + WB_QB;
    const int t = threadIdx.x, w = t >> 6, lane = t & 63;
    const int q0 = blockIdx.x * 32 + w * 8;
    const int b  = q0 >> 11;
    const float* M = wsf + WS_M + (size_t)b * D_ * D_;

    float qv[8], y[8] = {};
    #pragma unroll
    for (int r = 0; r < 8; ++r) qv[r] = bf2f(Qb[(size_t)(q0 + r) * D_ + lane]);
    for (int d2 = 0; d2 < 64; ++d2) {
        float m = M[d2 * D_ + lane];
        #pragma unroll
        for (int r = 0; r < 8; ++r) y[r] += __shfl(qv[r], d2, 64) * m;
    }
    float kl = wsf[WS_KSUM + b * D_ + lane];
    float z[8], sv[8];
    #pragma unroll
    for (int r = 0; r < 8; ++r) { z[r] = y[r] * qv[r]; sv[r] = qv[r] * kl; }
    #pragma unroll
    for (int m = 1; m < 64; m <<= 1) {
        #pragma unroll
        for (int r = 0; r < 8; ++r) {
            z[r]  += __shfl_xor(z[r],  m, 64);
            sv[r] += __shfl_xor(sv[r], m, 64);
        }
    }
    #pragma unroll
    for (int r = 0; r < 8; ++r) {
        if (lane == r) {
            float sum   = sv[r] * (1.0f / 32.0f);
            float sumsq = z[r]  * (1.0f / 1024.0f);
            float mu  = sum * (1.0f / 2048.0f);
            float var = (sumsq - sum * sum * (1.0f / 2048.0f)) * (1.0f / 2047.0f);
            var = fmaxf(var, 0.0f);
            float inv = 1.0f / (sqrtf(var) + 1e-8f);
            wsf[WS_A2 + q0 + r] = inv * (1.0f / 32.0f);
            wsf[WS_C2 + q0 + r] = -mu * inv;
        }
    }
}

// ---------------------------------------------------------------------------
// 5) MFMA flash attention.  grid (ROWS/128, 8 k-splits), block 256 (4 waves).
//    Wave owns 32 q rows; computes S^T = K.Q^T tiles, exp, P->LDS (bf16),
//    O += P.V via VT.  No __syncthreads: per-wave LDS region + lds_fence.
__global__ __launch_bounds__(256) void attention(float* __restrict__ wsf) {
    short* wsb = (short*)(wsf + WS_FEND);
    const short* Qb = wsb + WB_QB;
    const short* Kb = wsb + WB_KB;
    const short* VT = wsb + WB_VT;
    __shared__ short P[4][32][72];   // per-wave [32 q][64 keys], stride 72 (144B, 16B-aligned rows)

    const int t = threadIdx.x, w = t >> 6, lane = t & 63;
    const int l15 = lane & 15, g = lane >> 4;
    const int q0 = blockIdx.x * 128 + w * 32;
    const int b  = blockIdx.x >> 4;                 // 16 blocks per batch
    const int kb = blockIdx.y * (S_ / 8);           // 256-key range
    const size_t krow0 = (size_t)b * S_;

    // preload Q B-frags (B[d][q]) and per-q exp coefficients
    bf16x8 bq[2][2];
    float a2v[2], c2v[2];
    #pragma unroll
    for (int nt = 0; nt < 2; ++nt) {
        int q = q0 + nt*16 + l15;
        #pragma unroll
        for (int h = 0; h < 2; ++h)
            bq[nt][h] = ldb(&Qb[(size_t)q * D_ + h*32 + g*8]);
        a2v[nt] = wsf[WS_A2 + q];
        c2v[nt] = wsf[WS_C2 + q];
    }

    floatx4 O[2][4] = {};
    float sacc[2] = {0.0f, 0.0f};
    short* Pw = &P[w][0][0];

    for (int kc = 0; kc < S_ / 8; kc += 64) {
        const int key0 = kb + kc;
        // --- S^T tiles: Sc[kt][nt], D[key][q] ---
        floatx4 Sc[4][2] = {};
        #pragma unroll
        for (int kt = 0; kt < 4; ++kt) {
            const short* Krow = &Kb[(krow0 + key0 + kt*16 + l15) * D_];
            bf16x8 ak0 = ldb(&Krow[g*8]);
            bf16x8 ak1 = ldb(&Krow[32 + g*8]);
            #pragma unroll
            for (int nt = 0; nt < 2; ++nt) {
                Sc[kt][nt] = MFMA(ak0, bq[nt][0], Sc[kt][nt]);
                Sc[kt][nt] = MFMA(ak1, bq[nt][1], Sc[kt][nt]);
            }
        }
        lds_fence();   // WAR: previous chunk's P reads must finish
        // --- exp + pack bf16 + write P[q][key] (4 consecutive keys per write) ---
        #pragma unroll
        for (int nt = 0; nt < 2; ++nt) {
            const float aa = a2v[nt], cc = c2v[nt];
            #pragma unroll
            for (int kt = 0; kt < 4; ++kt) {
                float w0 = __expf(fmaf(Sc[kt][nt][0], aa, cc));
                float w1 = __expf(fmaf(Sc[kt][nt][1], aa, cc));
                float w2 = __expf(fmaf(Sc[kt][nt][2], aa, cc));
                float w3 = __expf(fmaf(Sc[kt][nt][3], aa, cc));
                sacc[nt] += (w0 + w1) + (w2 + w3);
                short4 pk;
                pk.x = (short)f2bf(w0); pk.y = (short)f2bf(w1);
                pk.z = (short)f2bf(w2); pk.w = (short)f2bf(w3);
                *(short4*)&Pw[(nt*16 + l15) * 72 + kt*16 + 4*g] = pk;
            }
        }
        lds_fence();   // RAW: make P visible to all lanes of this wave
        // --- PV: O[q][d] += P.V ---
        bf16x8 ap[2][2];
        #pragma unroll
        for (int mt = 0; mt < 2; ++mt)
            #pragma unroll
            for (int kh = 0; kh < 2; ++kh)
                ap[mt][kh] = ldb(&Pw[(mt*16 + l15) * 72 + kh*32 + g*8]);
        #pragma unroll
        for (int nt = 0; nt < 4; ++nt) {
            const short* Vrow = &VT[((size_t)b * D_ + nt*16 + l15) * S_ + key0];
            #pragma unroll
            for (int kh = 0; kh < 2; ++kh) {
                bf16x8 bv = ldb(&Vrow[kh*32 + g*8]);
                #pragma unroll
                for (int mt = 0; mt < 2; ++mt)
                    O[mt][nt] = MFMA(ap[mt][kh], bv, O[mt][nt]);
            }
        }
    }

    // --- epilogue: reduce sumw over g-groups, atomic accumulate ---
    #pragma unroll
    for (int nt = 0; nt < 2; ++nt) {
        sacc[nt] += __shfl_xor(sacc[nt], 16, 64);
        sacc[nt] += __shfl_xor(sacc[nt], 32, 64);
    }
    if (lane < 16) {
        atomicAdd(&wsf[WS_SUMW + q0 + lane],      sacc[0]);
        atomicAdd(&wsf[WS_SUMW + q0 + 16 + lane], sacc[1]);
    }
    #pragma unroll
    for (int mt = 0; mt < 2; ++mt)
        #pragma unroll
        for (int nt = 0; nt < 4; ++nt)
            #pragma unroll
            for (int r = 0; r < 4; ++r)
                atomicAdd(&wsf[WS_HEAD + (size_t)(q0 + mt*16 + 4*g + r) * D_ + nt*16 + l15],
                          O[mt][nt][r]);
}

// ---------------------------------------------------------------------------
// 6) out = (head/sumw) @ Weff + bout.   grid (ROWS/8, H/256), block 256.
__global__ __launch_bounds__(256) void finalize(
    const float* __restrict__ bout, const float* __restrict__ wsc,
    float* __restrict__ out)
{
    const int r0 = blockIdx.x * 8;
    const int c0 = blockIdx.y * 256;
    const int t  = threadIdx.x;
    __shared__ float hs[8][64];
    if (t < 128) {
        int r = t >> 4, c4 = t & 15;
        float inv = 1.0f / wsc[WS_SUMW + r0 + r];
        float4 h = *(const float4*)&wsc[WS_HEAD + (size_t)(r0 + r) * D_ + c4 * 4];
        h.x *= inv; h.y *= inv; h.z *= inv; h.w *= inv;
        *(float4*)&hs[r][c4*4] = h;
    }
    __syncthreads();

    const float* Wf = wsc + WS_WEFF;
    float acc[8] = {};
    #pragma unroll 4
    for (int d4 = 0; d4 < 16; ++d4) {
        float w0 = Wf[(size_t)(d4*4 + 0) * H_ + c0 + t];
        float w1 = Wf[(size_t)(d4*4 + 1) * H_ + c0 + t];
        float w2 = Wf[(size_t)(d4*4 + 2) * H_ + c0 + t];
        float w3 = Wf[(size_t)(d4*4 + 3) * H_ + c0 + t];
        #pragma unroll
        for (int r = 0; r < 8; ++r) {
            float4 h = *(const float4*)&hs[r][d4*4];
            acc[r] += h.x*w0 + h.y*w1 + h.z*w2 + h.w*w3;
        }
    }
    float bb = bout[c0 + t];
    #pragma unroll
    for (int r = 0; r < 8; ++r)
        out[(size_t)(r0 + r) * H_ + c0 + t] = acc[r] + bb;
}

// ---------------------------------------------------------------------------
extern "C" void kernel_launch(void* const* d_in, const int* in_sizes, int n_in,
                              void* d_out, int out_size, void* d_ws, size_t ws_size,
                              hipStream_t stream) {
    const float* query = (const float*)d_in[0];
    const float* key   = (const float*)d_in[1];
    const float* value = (const float*)d_in[2];
    // d_in[3] mask / d_in[12] seq_mask: adding -1e-32 is a no-op in fp32 -> never read.
    const float* Wq   = (const float*)d_in[4];
    const float* bq   = (const float*)d_in[5];
    const float* Wk   = (const float*)d_in[6];
    const float* bk   = (const float*)d_in[7];
    const float* Wv   = (const float*)d_in[8];
    const float* bv   = (const float*)d_in[9];
    const float* Wout = (const float*)d_in[10];
    const float* bout = (const float*)d_in[11];

    float* ws  = (float*)d_ws;   // ~6.1 MB used
    float* out = (float*)d_out;

    zero_ws<<<(NZERO + 255) / 256, 256, 0, stream>>>(ws);
    prep<<<(4 * D_ * H_) / 256, 256, 0, stream>>>(Wq, Wk, Wv, Wout, ws);
    qkv_mfma<<<dim3(ROWS/64, 3), 256, 0, stream>>>(query, key, value, bq, bk, bv, ws);
    kstats<<<B_ * 32, 256, 0, stream>>>(ws);
    rowstats<<<ROWS/32, 256, 0, stream>>>(ws);
    attention<<<dim3(ROWS/128, 8), 256, 0, stream>>>(ws);
    finalize<<<dim3(ROWS/8, H_/256), 256, 0, stream>>>(bout, ws, out);
}

// Round 3
// 248.588 us; speedup vs baseline: 1.6913x; 1.0605x over previous
//
#include <hip/hip_runtime.h>
#include <math.h>

// Problem constants
#define B_  4
#define S_  2048
#define H_  1024
#define D_  64
#define ROWS (B_*S_)      // 8192
#define KSPLIT 8
#define LOG2E 1.4426950408889634f

typedef __attribute__((ext_vector_type(4))) float  floatx4;
typedef __attribute__((ext_vector_type(8))) short  short8;
typedef __attribute__((ext_vector_type(8))) __bf16 bf16x8;

// ---- workspace layout (total ~13.5 MB) ----
// float region (offsets in floats):
#define WS_KSUM 0                          // [B][D]
#define WS_M    (WS_KSUM + B_*D_)          // [B][D][D]  K^T K per batch
#define WS_A2   (WS_M + B_*D_*D_)          // ROWS  inv/32*log2e
#define WS_C2   (WS_A2 + ROWS)             // ROWS  -mu*inv*log2e
#define WS_SWP  (WS_C2 + ROWS)             // [KSPLIT][ROWS] sumw partials
#define WS_FEND (WS_SWP + KSPLIT*ROWS)     // 98560 floats (16B-aligned *4)
// bf16(short) region, starts right after the float region:
#define WB_QB    0                          // [ROWS][64]
#define WB_KB    (WB_QB + ROWS*D_)          // [ROWS][64]
#define WB_VT    (WB_KB + ROWS*D_)          // [B][64][2048]  V transposed
#define WB_WT    (WB_VT + ROWS*D_)          // [3][64][1024]  W transposed bf16
#define WB_WEFFT (WB_WT + 3*D_*H_)          // [H][64]  Weff transposed bf16
#define WB_HN    (WB_WEFFT + H_*D_)         // [ROWS][64] normalized head bf16
#define WB_OP    (WB_HN + ROWS*D_)          // [KSPLIT][ROWS][64] O partials bf16
#define NZ2      (B_*D_ + B_*D_*D_)         // zeroed atomically-accumulated range

__device__ __forceinline__ unsigned short f2bf(float f) {
    union { float f; unsigned u; } v; v.f = f;
    unsigned r = v.u + 0x7FFFu + ((v.u >> 16) & 1u);   // RNE
    return (unsigned short)(r >> 16);
}
__device__ __forceinline__ float bf2f(short s) {
    union { unsigned u; float f; } v;
    v.u = ((unsigned)(unsigned short)s) << 16; return v.f;
}
__device__ __forceinline__ bf16x8 ldb(const short* p) {
    union { short8 s; bf16x8 b; } u; u.s = *(const short8*)p; return u.b;
}
#define MFMA(a,b,c) __builtin_amdgcn_mfma_f32_16x16x32_bf16(a, b, c, 0, 0, 0)
// per-wave LDS ordering fence: lgkmcnt(0) only, vmcnt stays in flight
__device__ __forceinline__ void lds_fence() {
    __builtin_amdgcn_wave_barrier();
    __builtin_amdgcn_s_waitcnt(0xc07f);
    __builtin_amdgcn_wave_barrier();
}

// ---------------------------------------------------------------------------
// 1) prep: [0,768) WT bf16 transpose; [768,784) WeffT bf16; [784,849) zero M/KSUM
__global__ __launch_bounds__(256) void prep(
    const float* __restrict__ Wq, const float* __restrict__ Wk,
    const float* __restrict__ Wv, const float* __restrict__ Wout,
    float* __restrict__ wsf)
{
    __shared__ float tile[64][65];
    short* wsb = (short*)(wsf + WS_FEND);
    const int bx = blockIdx.x, t = threadIdx.x;
    if (bx < 768) {
        int idx = bx * 256 + t;              // < 3*64*1024
        int mat = idx >> 16, rem = idx & 65535;
        int n = rem >> 10, k = rem & 1023;
        const float* W = (mat == 0) ? Wq : (mat == 1) ? Wk : Wv;
        wsb[WB_WT + idx] = (short)f2bf(W[(size_t)k * D_ + n]);
    } else if (bx < 784) {
        // WeffT[n][d] = sum_h Wout[h*64+d][n], bf16
        int n0 = (bx - 768) * 64;
        int nn = t & 63, dg = t >> 6;
        for (int dd = 0; dd < 16; ++dd) {
            int d = dg * 16 + dd;
            float s = 0.0f;
            #pragma unroll
            for (int h = 0; h < 16; ++h)
                s += Wout[(size_t)(h * 64 + d) * H_ + n0 + nn];
            tile[d][nn] = s;
        }
        __syncthreads();
        int n = t >> 2, d0 = (t & 3) * 16;
        short* dst = wsb + WB_WEFFT + (size_t)(n0 + n) * D_ + d0;
        #pragma unroll
        for (int j = 0; j < 16; ++j) dst[j] = (short)f2bf(tile[d0 + j][n]);
    } else {
        int i = (bx - 784) * 256 + t;
        if (i < NZ2) wsf[WS_KSUM + i] = 0.0f;
    }
}

// ---------------------------------------------------------------------------
// 2) q/k/v = bf16(X @ W + b) via MFMA, K-split over the block's 4 waves.
//    grid (ROWS/16, 3), block 256.  Wave w handles K slice [w*256, w*256+256).
__global__ __launch_bounds__(256) void qkv_mfma(
    const float* __restrict__ query, const float* __restrict__ key,
    const float* __restrict__ value,
    const float* __restrict__ bq, const float* __restrict__ bk,
    const float* __restrict__ bvp, float* __restrict__ wsf)
{
    short* wsb = (short*)(wsf + WS_FEND);
    const int mat = blockIdx.y;
    const float* X    = (mat == 0) ? query : (mat == 1) ? key : value;
    const float* bias = (mat == 0) ? bq    : (mat == 1) ? bk  : bvp;
    const short* WT = wsb + WB_WT + mat * (D_ * H_);

    const int t = threadIdx.x, w = t >> 6, lane = t & 63;
    const int l15 = lane & 15, g = lane >> 4;
    const int r0 = blockIdx.x * 16;
    const float* Xrow = X + (size_t)(r0 + l15) * H_ + w * 256;

    floatx4 acc[4] = {};
    #pragma unroll
    for (int ki = 0; ki < 8; ++ki) {
        int k = ki * 32 + g * 8;
        float4 a0 = *(const float4*)&Xrow[k];
        float4 a1 = *(const float4*)&Xrow[k + 4];
        union { short8 s; bf16x8 b; } uf;
        uf.s[0]=(short)f2bf(a0.x); uf.s[1]=(short)f2bf(a0.y);
        uf.s[2]=(short)f2bf(a0.z); uf.s[3]=(short)f2bf(a0.w);
        uf.s[4]=(short)f2bf(a1.x); uf.s[5]=(short)f2bf(a1.y);
        uf.s[6]=(short)f2bf(a1.z); uf.s[7]=(short)f2bf(a1.w);
        #pragma unroll
        for (int nt = 0; nt < 4; ++nt) {
            bf16x8 bf = ldb(&WT[(size_t)(nt*16 + l15) * H_ + w * 256 + k]);
            acc[nt] = MFMA(uf.b, bf, acc[nt]);
        }
    }

    // cross-wave reduction through LDS (row stride 68 -> 2-way max, free)
    __shared__ float red[4][16][68];
    #pragma unroll
    for (int nt = 0; nt < 4; ++nt)
        #pragma unroll
        for (int r = 0; r < 4; ++r)
            red[w][4*g + r][nt*16 + l15] = acc[nt][r];
    __syncthreads();

    if (mat < 2) {
        short* OUT = wsb + ((mat == 0) ? WB_QB : WB_KB);
        int row = t >> 4, c4 = t & 15, n = c4 * 4;
        float4 s = {0.f, 0.f, 0.f, 0.f};
        #pragma unroll
        for (int w2 = 0; w2 < 4; ++w2) {
            float4 v = *(const float4*)&red[w2][row][n];
            s.x += v.x; s.y += v.y; s.z += v.z; s.w += v.w;
        }
        short4 pk;
        pk.x = (short)f2bf(s.x + bias[n+0]); pk.y = (short)f2bf(s.y + bias[n+1]);
        pk.z = (short)f2bf(s.z + bias[n+2]); pk.w = (short)f2bf(s.w + bias[n+3]);
        *(short4*)&OUT[(size_t)(r0 + row) * D_ + n] = pk;
    } else {
        short* VT = wsb + WB_VT;
        int d = t >> 2, rq = (t & 3) * 4;
        float v[4] = {};
        #pragma unroll
        for (int w2 = 0; w2 < 4; ++w2)
            #pragma unroll
            for (int j = 0; j < 4; ++j)
                v[j] += red[w2][rq + j][d];
        float bb = bias[d];
        short4 pk;
        pk.x = (short)f2bf(v[0] + bb); pk.y = (short)f2bf(v[1] + bb);
        pk.z = (short)f2bf(v[2] + bb); pk.w = (short)f2bf(v[3] + bb);
        int b = r0 >> 11, srow = (r0 & (S_ - 1)) + rq;
        *(short4*)&VT[((size_t)b * D_ + d) * S_ + srow] = pk;
    }
}

// ---------------------------------------------------------------------------
// 3) per-batch K column sums and M = K^T K (fp32 from bf16 K).
__global__ __launch_bounds__(256) void kstats(float* __restrict__ wsf) {
    const short* Kb = (short*)(wsf + WS_FEND) + WB_KB;
    const int b     = blockIdx.x >> 5;
    const int chunk = blockIdx.x & 31;
    const size_t base = ((size_t)b * S_ + chunk * 64) * D_;

    __shared__ float kt[64][64];
    const int t = threadIdx.x;
    #pragma unroll
    for (int u = 0; u < 2; ++u) {
        int c = t + u * 256;              // 0..511 chunks of 8
        int j = c >> 3, c8 = c & 7;
        short8 kv = *(const short8*)&Kb[base + (size_t)j * D_ + c8 * 8];
        #pragma unroll
        for (int i = 0; i < 8; ++i) kt[j][c8*8 + i] = bf2f(kv[i]);
    }
    __syncthreads();

    const int td = t >> 4, te = t & 15;
    float acc[4][4] = {};
    for (int j = 0; j < 64; ++j) {
        float4 a  = *(const float4*)&kt[j][td*4];
        float4 bb = *(const float4*)&kt[j][te*4];
        float av[4] = {a.x, a.y, a.z, a.w};
        float bw[4] = {bb.x, bb.y, bb.z, bb.w};
        #pragma unroll
        for (int i = 0; i < 4; ++i)
            #pragma unroll
            for (int l = 0; l < 4; ++l)
                acc[i][l] += av[i] * bw[l];
    }
    float* M = wsf + WS_M + (size_t)b * D_ * D_;
    #pragma unroll
    for (int i = 0; i < 4; ++i)
        #pragma unroll
        for (int l = 0; l < 4; ++l)
            atomicAdd(&M[(td*4 + i) * D_ + te*4 + l], acc[i][l]);

    if (t < 64) {
        float s = 0.0f;
        for (int j = 0; j < 64; ++j) s += kt[j][t];
        atomicAdd(&wsf[WS_KSUM + b * D_ + t], s);
    }
}

// ---------------------------------------------------------------------------
// 4) row stats -> a2 = inv/32*log2e, c2 = -mu*inv*log2e.  8 rows/wave.
__global__ __launch_bounds__(256) void rowstats(float* __restrict__ wsf) {
    const short* Qb = (short*)(wsf + WS_FEND) + WB_QB;
    const int t = threadIdx.x, w = t >> 6, lane = t & 63;
    const int q0 = blockIdx.x * 32 + w * 8;
    const int b  = q0 >> 11;
    const float* M = wsf + WS_M + (size_t)b * D_ * D_;

    float qv[8], y[8] = {};
    #pragma unroll
    for (int r = 0; r < 8; ++r) qv[r] = bf2f(Qb[(size_t)(q0 + r) * D_ + lane]);
    for (int d2 = 0; d2 < 64; ++d2) {
        float m = M[d2 * D_ + lane];
        #pragma unroll
        for (int r = 0; r < 8; ++r) y[r] += __shfl(qv[r], d2, 64) * m;
    }
    float kl = wsf[WS_KSUM + b * D_ + lane];
    float z[8], sv[8];
    #pragma unroll
    for (int r = 0; r < 8; ++r) { z[r] = y[r] * qv[r]; sv[r] = qv[r] * kl; }
    #pragma unroll
    for (int m = 1; m < 64; m <<= 1) {
        #pragma unroll
        for (int r = 0; r < 8; ++r) {
            z[r]  += __shfl_xor(z[r],  m, 64);
            sv[r] += __shfl_xor(sv[r], m, 64);
        }
    }
    #pragma unroll
    for (int r = 0; r < 8; ++r) {
        if (lane == r) {
            float sum   = sv[r] * (1.0f / 32.0f);
            float sumsq = z[r]  * (1.0f / 1024.0f);
            float mu  = sum * (1.0f / 2048.0f);
            float var = (sumsq - sum * sum * (1.0f / 2048.0f)) * (1.0f / 2047.0f);
            var = fmaxf(var, 0.0f);
            float inv = 1.0f / (sqrtf(var) + 1e-8f);
            wsf[WS_A2 + q0 + r] = inv * (LOG2E / 32.0f);
            wsf[WS_C2 + q0 + r] = -mu * inv * LOG2E;
        }
    }
}

// ---------------------------------------------------------------------------
// 5) MFMA flash attention.  grid (ROWS/128, KSPLIT), block 256 (4 waves).
//    Wave owns 32 q rows; partials stored (bf16 O, fp32 sumw) -> no atomics.
__global__ __launch_bounds__(256) void attention(float* __restrict__ wsf) {
    short* wsb = (short*)(wsf + WS_FEND);
    const short* Qb = wsb + WB_QB;
    const short* Kb = wsb + WB_KB;
    const short* VT = wsb + WB_VT;
    __shared__ short P[4][32][72];   // per-wave [32 q][64 keys]

    const int t = threadIdx.x, w = t >> 6, lane = t & 63;
    const int l15 = lane & 15, g = lane >> 4;
    const int q0 = blockIdx.x * 128 + w * 32;
    const int b  = blockIdx.x >> 4;                 // 16 blocks per batch
    const int kb = blockIdx.y * (S_ / KSPLIT);      // 256-key range
    const size_t krow0 = (size_t)b * S_;

    // preload Q B-frags (B[d][q]) and per-q exp2 coefficients
    bf16x8 bqf[2][2];
    float a2v[2], c2v[2];
    #pragma unroll
    for (int nt = 0; nt < 2; ++nt) {
        int q = q0 + nt*16 + l15;
        #pragma unroll
        for (int h = 0; h < 2; ++h)
            bqf[nt][h] = ldb(&Qb[(size_t)q * D_ + h*32 + g*8]);
        a2v[nt] = wsf[WS_A2 + q];
        c2v[nt] = wsf[WS_C2 + q];
    }

    floatx4 O[2][4] = {};
    float sacc[2] = {0.0f, 0.0f};
    short* Pw = &P[w][0][0];

    for (int kc = 0; kc < S_ / KSPLIT; kc += 64) {
        const int key0 = kb + kc;
        // --- S^T tiles: Sc[kt][nt], D[key][q] ---
        floatx4 Sc[4][2] = {};
        #pragma unroll
        for (int kt = 0; kt < 4; ++kt) {
            const short* Krow = &Kb[(krow0 + key0 + kt*16 + l15) * D_];
            bf16x8 ak0 = ldb(&Krow[g*8]);
            bf16x8 ak1 = ldb(&Krow[32 + g*8]);
            #pragma unroll
            for (int nt = 0; nt < 2; ++nt) {
                Sc[kt][nt] = MFMA(ak0, bqf[nt][0], Sc[kt][nt]);
                Sc[kt][nt] = MFMA(ak1, bqf[nt][1], Sc[kt][nt]);
            }
        }
        lds_fence();   // WAR: previous chunk's P reads must finish
        // --- exp2 + pack bf16 + write P[q][key] ---
        #pragma unroll
        for (int nt = 0; nt < 2; ++nt) {
            const float aa = a2v[nt], cc = c2v[nt];
            #pragma unroll
            for (int kt = 0; kt < 4; ++kt) {
                float w0 = exp2f(fmaf(Sc[kt][nt][0], aa, cc));
                float w1 = exp2f(fmaf(Sc[kt][nt][1], aa, cc));
                float w2 = exp2f(fmaf(Sc[kt][nt][2], aa, cc));
                float w3 = exp2f(fmaf(Sc[kt][nt][3], aa, cc));
                sacc[nt] += (w0 + w1) + (w2 + w3);
                short4 pk;
                pk.x = (short)f2bf(w0); pk.y = (short)f2bf(w1);
                pk.z = (short)f2bf(w2); pk.w = (short)f2bf(w3);
                *(short4*)&Pw[(nt*16 + l15) * 72 + kt*16 + 4*g] = pk;
            }
        }
        lds_fence();   // RAW: make P visible to all lanes of this wave
        // --- PV: O[q][d] += P.V ---
        bf16x8 ap[2][2];
        #pragma unroll
        for (int mt = 0; mt < 2; ++mt)
            #pragma unroll
            for (int kh = 0; kh < 2; ++kh)
                ap[mt][kh] = ldb(&Pw[(mt*16 + l15) * 72 + kh*32 + g*8]);
        #pragma unroll
        for (int nt = 0; nt < 4; ++nt) {
            const short* Vrow = &VT[((size_t)b * D_ + nt*16 + l15) * S_ + key0];
            #pragma unroll
            for (int kh = 0; kh < 2; ++kh) {
                bf16x8 bv = ldb(&Vrow[kh*32 + g*8]);
                #pragma unroll
                for (int mt = 0; mt < 2; ++mt)
                    O[mt][nt] = MFMA(ap[mt][kh], bv, O[mt][nt]);
            }
        }
    }

    // --- epilogue: reduce sumw over g-groups; store partials (no atomics) ---
    #pragma unroll
    for (int nt = 0; nt < 2; ++nt) {
        sacc[nt] += __shfl_xor(sacc[nt], 16, 64);
        sacc[nt] += __shfl_xor(sacc[nt], 32, 64);
    }
    if (lane < 16) {
        wsf[WS_SWP + blockIdx.y * ROWS + q0 + lane]      = sacc[0];
        wsf[WS_SWP + blockIdx.y * ROWS + q0 + 16 + lane] = sacc[1];
    }
    short* OP = wsb + WB_OP + ((size_t)blockIdx.y * ROWS + q0) * D_;
    #pragma unroll
    for (int mt = 0; mt < 2; ++mt)
        #pragma unroll
        for (int nt = 0; nt < 4; ++nt)
            #pragma unroll
            for (int r = 0; r < 4; ++r)
                OP[(size_t)(mt*16 + 4*g + r) * D_ + nt*16 + l15] =
                    (short)f2bf(O[mt][nt][r]);
}

// ---------------------------------------------------------------------------
// 6) reduce partials -> HN bf16 = (sum_p OP) / (sum_p SW).  grid ROWS/32.
__global__ __launch_bounds__(256) void reduceo(float* __restrict__ wsf) {
    short* wsb = (short*)(wsf + WS_FEND);
    const short* OP = wsb + WB_OP;
    short* HN = wsb + WB_HN;
    const int t = threadIdx.x;
    const int row = blockIdx.x * 32 + (t >> 3);
    const int c8 = (t & 7) * 8;
    float sw = 0.0f;
    #pragma unroll
    for (int p = 0; p < KSPLIT; ++p) sw += wsf[WS_SWP + p * ROWS + row];
    float inv = 1.0f / sw;
    float a[8] = {};
    #pragma unroll
    for (int p = 0; p < KSPLIT; ++p) {
        short8 o = *(const short8*)&OP[((size_t)p * ROWS + row) * D_ + c8];
        #pragma unroll
        for (int j = 0; j < 8; ++j) a[j] += bf2f(o[j]);
    }
    short8 hn;
    #pragma unroll
    for (int j = 0; j < 8; ++j) hn[j] = (short)f2bf(a[j] * inv);
    *(short8*)&HN[(size_t)row * D_ + c8] = hn;
}

// ---------------------------------------------------------------------------
// 7) out = HN @ Weff + bout via MFMA (K=64).  grid (ROWS/64, H/64), block 256.
__global__ __launch_bounds__(256) void finalize(
    const float* __restrict__ bout, const float* __restrict__ wsf,
    float* __restrict__ out)
{
    const short* wsb = (const short*)(wsf + WS_FEND);
    const short* HN  = wsb + WB_HN;
    const short* WfT = wsb + WB_WEFFT;
    const int t = threadIdx.x, w = t >> 6, lane = t & 63;
    const int l15 = lane & 15, g = lane >> 4;
    const int r0 = blockIdx.x * 64 + w * 16;
    const int c0 = blockIdx.y * 64;

    bf16x8 ah[2];
    #pragma unroll
    for (int h = 0; h < 2; ++h)
        ah[h] = ldb(&HN[(size_t)(r0 + l15) * D_ + h*32 + g*8]);

    floatx4 acc[4] = {};
    #pragma unroll
    for (int nt = 0; nt < 4; ++nt) {
        #pragma unroll
        for (int h = 0; h < 2; ++h) {
            bf16x8 bf = ldb(&WfT[(size_t)(c0 + nt*16 + l15) * D_ + h*32 + g*8]);
            acc[nt] = MFMA(ah[h], bf, acc[nt]);
        }
    }
    #pragma unroll
    for (int nt = 0; nt < 4; ++nt) {
        int col = c0 + nt*16 + l15;
        float bb = bout[col];
        #pragma unroll
        for (int r = 0; r < 4; ++r)
            out[(size_t)(r0 + 4*g + r) * H_ + col] = acc[nt][r] + bb;
    }
}

// ---------------------------------------------------------------------------
extern "C" void kernel_launch(void* const* d_in, const int* in_sizes, int n_in,
                              void* d_out, int out_size, void* d_ws, size_t ws_size,
                              hipStream_t stream) {
    const float* query = (const float*)d_in[0];
    const float* key   = (const float*)d_in[1];
    const float* value = (const float*)d_in[2];
    // d_in[3] mask / d_in[12] seq_mask: adding -1e-32 is a no-op in fp32 -> never read.
    const float* Wq   = (const float*)d_in[4];
    const float* bq   = (const float*)d_in[5];
    const float* Wk   = (const float*)d_in[6];
    const float* bk   = (const float*)d_in[7];
    const float* Wv   = (const float*)d_in[8];
    const float* bv   = (const float*)d_in[9];
    const float* Wout = (const float*)d_in[10];
    const float* bout = (const float*)d_in[11];

    float* ws  = (float*)d_ws;   // ~13.5 MB used
    float* out = (float*)d_out;

    prep<<<849, 256, 0, stream>>>(Wq, Wk, Wv, Wout, ws);
    qkv_mfma<<<dim3(ROWS/16, 3), 256, 0, stream>>>(query, key, value, bq, bk, bv, ws);
    kstats<<<B_ * 32, 256, 0, stream>>>(ws);
    rowstats<<<ROWS/32, 256, 0, stream>>>(ws);
    attention<<<dim3(ROWS/128, KSPLIT), 256, 0, stream>>>(ws);
    reduceo<<<ROWS/32, 256, 0, stream>>>(ws);
    finalize<<<dim3(ROWS/64, H_/64), 256, 0, stream>>>(bout, ws, out);
}

// Round 4
// 219.533 us; speedup vs baseline: 1.9152x; 1.1324x over previous
//
#include <hip/hip_runtime.h>
#include <math.h>

// Problem constants
#define B_  4
#define S_  2048
#define H_  1024
#define D_  64
#define ROWS (B_*S_)      // 8192
#define KSPLIT 8
#define LOG2E 1.4426950408889634f

typedef __attribute__((ext_vector_type(4))) float  floatx4;
typedef __attribute__((ext_vector_type(8))) short  short8;
typedef __attribute__((ext_vector_type(8))) __bf16 bf16x8;

// ---- workspace layout (~13.5 MB) ----
// float region (offsets in floats):
#define WS_KSUM 0                          // [B][D]
#define WS_M    (WS_KSUM + B_*D_)          // [B][D][D]  K^T K per batch
#define WS_A2   (WS_M + B_*D_*D_)          // ROWS  inv/32*log2e
#define WS_C2   (WS_A2 + ROWS)             // ROWS  -mu*inv*log2e
#define WS_SWP  (WS_C2 + ROWS)             // [KSPLIT][ROWS] sumw partials
#define WS_FEND (WS_SWP + KSPLIT*ROWS)     // 98560 floats (x4 B = 16B-aligned)
// bf16(short) region, starts right after the float region.
// Fragment-major layouts: [..][lane 0..63][j 0..7] so one 16B load per lane is
// a contiguous 1KB wave access (fixes the 16-line-scatter TA bottleneck).
#define WB_QB  0                           // [ROWS][64] row-major (rowstats + attn Q-frags)
#define WB_KF  (WB_QB + ROWS*D_)           // [ROWS/16][kh2][64][8]  K A-frags
#define WB_VF  (WB_KF + ROWS*D_)           // [ROWS/64][nt4][kh2][64][8]  V B-frags
#define WB_WT  (WB_VF + ROWS*D_)           // [3][32 kc][4 nt][64][8]  W B-frags
#define WB_WFF (WB_WT + 3*D_*H_)           // [H/16][2][64][8]  Weff B-frags
#define WB_HNF (WB_WFF + H_*D_)            // [ROWS/16][2][64][8]  head A-frags
#define WB_OP  (WB_HNF + ROWS*D_)          // [KSPLIT][ROWS][64] O partials bf16
#define NZ2    (B_*D_ + B_*D_*D_)          // zeroed atomically-accumulated range

__device__ __forceinline__ unsigned short f2bf(float f) {
    union { float f; unsigned u; } v; v.f = f;
    unsigned r = v.u + 0x7FFFu + ((v.u >> 16) & 1u);   // RNE
    return (unsigned short)(r >> 16);
}
__device__ __forceinline__ short bfc(float f) {        // HW cvt (RNE) path
    __bf16 h = (__bf16)f;
    short s; __builtin_memcpy(&s, &h, 2); return s;
}
__device__ __forceinline__ float bf2f(short s) {
    union { unsigned u; float f; } v;
    v.u = ((unsigned)(unsigned short)s) << 16; return v.f;
}
__device__ __forceinline__ bf16x8 ldb(const short* p) {
    union { short8 s; bf16x8 b; } u; u.s = *(const short8*)p; return u.b;
}
#define MFMA(a,b,c) __builtin_amdgcn_mfma_f32_16x16x32_bf16(a, b, c, 0, 0, 0)
// per-wave LDS ordering fence: lgkmcnt(0) only, vmcnt stays in flight
__device__ __forceinline__ void lds_fence() {
    __builtin_amdgcn_wave_barrier();
    __builtin_amdgcn_s_waitcnt(0xc07f);
    __builtin_amdgcn_wave_barrier();
}

// ---------------------------------------------------------------------------
// 1) prep:
//    bx [0,96):    WT3 fragment-major gather of Wq/Wk/Wv (bf16)
//    bx [96,112):  WFF = fragment-major bf16 of Weff^T (sum of Wout blocks)
//    bx [112,177): zero KSUM+M
__global__ __launch_bounds__(256) void prep(
    const float* __restrict__ Wq, const float* __restrict__ Wk,
    const float* __restrict__ Wv, const float* __restrict__ Wout,
    float* __restrict__ wsf)
{
    __shared__ float tile[64][65];
    short* wsb = (short*)(wsf + WS_FEND);
    const int bx = blockIdx.x, t = threadIdx.x;
    if (bx < 96) {
        int idx = bx * 256 + t;              // slot < 3*32*4*64
        int mat = idx >> 13, rem = idx & 8191;
        int kc = rem >> 8, nt = (rem >> 6) & 3, lane = rem & 63;
        int g = lane >> 4, l15 = lane & 15;
        const float* W = (mat == 0) ? Wq : (mat == 1) ? Wk : Wv;
        short8 fr;
        #pragma unroll
        for (int j = 0; j < 8; ++j)
            fr[j] = (short)f2bf(W[(size_t)(kc*32 + g*8 + j) * D_ + nt*16 + l15]);
        *(short8*)&wsb[WB_WT + (size_t)idx * 8] = fr;
    } else if (bx < 112) {
        // Weff[d][n] = sum_h Wout[h*64+d][n]
        int n0 = (bx - 96) * 64;
        int nn = t & 63, dg = t >> 6;
        for (int dd = 0; dd < 16; ++dd) {
            int d = dg * 16 + dd;
            float s = 0.0f;
            #pragma unroll
            for (int h = 0; h < 16; ++h)
                s += Wout[(size_t)(h * 64 + d) * H_ + n0 + nn];
            tile[d][nn] = s;
        }
        __syncthreads();
        #pragma unroll
        for (int u = 0; u < 2; ++u) {
            int s = 2*t + u;                 // slot < 512
            int ctl = s >> 7, h = (s >> 6) & 1, lane = s & 63;
            int g = lane >> 4, l2 = lane & 15;
            short8 fr;
            #pragma unroll
            for (int j = 0; j < 8; ++j)
                fr[j] = (short)f2bf(tile[h*32 + g*8 + j][ctl*16 + l2]);
            *(short8*)&wsb[WB_WFF + (size_t)((((n0 >> 4) + ctl)*2 + h)*64 + lane) * 8] = fr;
        }
    } else {
        int i = (bx - 112) * 256 + t;
        if (i < NZ2) wsf[WS_KSUM + i] = 0.0f;
    }
}

// ---------------------------------------------------------------------------
// 2) q/k/v = bf16(X @ W + b) via MFMA.  grid (ROWS/32, 3), block 256.
//    X staged through LDS (coalesced 512B global segments), W from WT3 frags
//    (contiguous 1KB wave loads).  Wave w: rows (w>>1)*16, n-half (w&1).
__global__ __launch_bounds__(256) void qkv_mfma(
    const float* __restrict__ query, const float* __restrict__ key,
    const float* __restrict__ value,
    const float* __restrict__ bq, const float* __restrict__ bk,
    const float* __restrict__ bvp, float* __restrict__ wsf)
{
    short* wsb = (short*)(wsf + WS_FEND);
    const int mat = blockIdx.y;
    const float* X    = (mat == 0) ? query : (mat == 1) ? key : value;
    const float* bias = (mat == 0) ? bq    : (mat == 1) ? bk  : bvp;
    const short* WT3 = wsb + WB_WT + (size_t)mat * (D_ * H_);

    const int t = threadIdx.x, w = t >> 6, lane = t & 63;
    const int l15 = lane & 15, g = lane >> 4;
    const int r0 = blockIdx.x * 32;
    const int mrow0 = (w >> 1) * 16;
    const int nt0 = (w & 1) * 2;

    __shared__ short xs[32][136];   // bf16 X tile, stride 136: conflict-free family
    floatx4 acc[2] = {};

    for (int step = 0; step < 8; ++step) {
        __syncthreads();
        #pragma unroll
        for (int u = 0; u < 4; ++u) {
            int row = u * 8 + (t >> 5), col = (t & 31) * 4;
            float4 xv = *(const float4*)&X[(size_t)(r0 + row) * H_ + step * 128 + col];
            short4 pk;
            pk.x = bfc(xv.x); pk.y = bfc(xv.y); pk.z = bfc(xv.z); pk.w = bfc(xv.w);
            *(short4*)&xs[row][col] = pk;
        }
        __syncthreads();
        #pragma unroll
        for (int kk = 0; kk < 4; ++kk) {
            bf16x8 a = ldb(&xs[mrow0 + l15][kk * 32 + g * 8]);
            int kc = step * 4 + kk;
            #pragma unroll
            for (int n = 0; n < 2; ++n) {
                bf16x8 bf = ldb(&WT3[(size_t)((kc * 4) + nt0 + n) * 512 + lane * 8]);
                acc[n] = MFMA(a, bf, acc[n]);
            }
        }
    }

    // epilogue: C layout row=4g+r (in 16-tile), col=l15
    if (mat == 0) {
        short* QB = wsb + WB_QB;
        #pragma unroll
        for (int n = 0; n < 2; ++n) {
            int col = (nt0 + n) * 16 + l15;
            float bb = bias[col];
            #pragma unroll
            for (int r = 0; r < 4; ++r)
                QB[(size_t)(r0 + mrow0 + 4*g + r) * D_ + col] = (short)f2bf(acc[n][r] + bb);
        }
    } else if (mat == 1) {
        short* KF = wsb + WB_KF;
        #pragma unroll
        for (int n = 0; n < 2; ++n) {
            int d = (nt0 + n) * 16 + l15;
            int kh = d >> 5, gk = (d >> 3) & 3, j = d & 7;
            float bb = bias[d];
            #pragma unroll
            for (int r = 0; r < 4; ++r) {
                int R = r0 + mrow0 + 4*g + r;
                KF[(size_t)(((R >> 4) * 2 + kh) * 64 + gk * 16 + (R & 15)) * 8 + j] =
                    (short)f2bf(acc[n][r] + bb);
            }
        }
    } else {
        short* VF = wsb + WB_VF;
        int R0 = r0 + mrow0 + 4*g;
        int kh = (R0 >> 5) & 1, gv = (R0 >> 3) & 3, j0 = R0 & 7, blk = R0 >> 6;
        #pragma unroll
        for (int n = 0; n < 2; ++n) {
            int d = (nt0 + n) * 16 + l15;
            int ntv = d >> 4;
            float bb = bias[d];
            short4 pk;
            pk.x = (short)f2bf(acc[n][0] + bb); pk.y = (short)f2bf(acc[n][1] + bb);
            pk.z = (short)f2bf(acc[n][2] + bb); pk.w = (short)f2bf(acc[n][3] + bb);
            *(short4*)&VF[(size_t)(((blk * 4 + ntv) * 2 + kh) * 64 + gv * 16 + (d & 15)) * 8 + j0] = pk;
        }
    }
}

// ---------------------------------------------------------------------------
// 3) per-batch K column sums and M = K^T K (decodes KF fragments).
__global__ __launch_bounds__(256) void kstats(float* __restrict__ wsf) {
    const short* KF = (short*)(wsf + WS_FEND) + WB_KF;
    const int b     = blockIdx.x >> 5;
    const int chunk = blockIdx.x & 31;
    const int keyblk0 = b * 128 + chunk * 4;

    __shared__ float kt[64][64];
    const int t = threadIdx.x;
    #pragma unroll
    for (int u = 0; u < 2; ++u) {
        int s = 2*t + u;                       // slot < 512
        int kb4 = s >> 7, kh = (s >> 6) & 1, lane2 = s & 63;
        int g2 = lane2 >> 4, l2 = lane2 & 15;
        short8 v = *(const short8*)&KF[(size_t)(((keyblk0 + kb4) * 2 + kh) * 64 + lane2) * 8];
        #pragma unroll
        for (int j = 0; j < 8; ++j)
            kt[kb4 * 16 + l2][kh * 32 + g2 * 8 + j] = bf2f(v[j]);
    }
    __syncthreads();

    const int td = t >> 4, te = t & 15;
    float acc[4][4] = {};
    for (int j = 0; j < 64; ++j) {
        float4 a  = *(const float4*)&kt[j][td*4];
        float4 bb = *(const float4*)&kt[j][te*4];
        float av[4] = {a.x, a.y, a.z, a.w};
        float bw[4] = {bb.x, bb.y, bb.z, bb.w};
        #pragma unroll
        for (int i = 0; i < 4; ++i)
            #pragma unroll
            for (int l = 0; l < 4; ++l)
                acc[i][l] += av[i] * bw[l];
    }
    float* M = wsf + WS_M + (size_t)b * D_ * D_;
    #pragma unroll
    for (int i = 0; i < 4; ++i)
        #pragma unroll
        for (int l = 0; l < 4; ++l)
            atomicAdd(&M[(td*4 + i) * D_ + te*4 + l], acc[i][l]);

    if (t < 64) {
        float s = 0.0f;
        for (int j = 0; j < 64; ++j) s += kt[j][t];
        atomicAdd(&wsf[WS_KSUM + b * D_ + t], s);
    }
}

// ---------------------------------------------------------------------------
// 4) row stats -> a2 = inv/32*log2e, c2 = -mu*inv*log2e.  8 rows/wave.
__global__ __launch_bounds__(256) void rowstats(float* __restrict__ wsf) {
    const short* Qb = (short*)(wsf + WS_FEND) + WB_QB;
    const int t = threadIdx.x, w = t >> 6, lane = t & 63;
    const int q0 = blockIdx.x * 32 + w * 8;
    const int b  = q0 >> 11;
    const float* M = wsf + WS_M + (size_t)b * D_ * D_;

    float qv[8], y[8] = {};
    #pragma unroll
    for (int r = 0; r < 8; ++r) qv[r] = bf2f(Qb[(size_t)(q0 + r) * D_ + lane]);
    for (int d2 = 0; d2 < 64; ++d2) {
        float m = M[d2 * D_ + lane];
        #pragma unroll
        for (int r = 0; r < 8; ++r) y[r] += __shfl(qv[r], d2, 64) * m;
    }
    float kl = wsf[WS_KSUM + b * D_ + lane];
    float z[8], sv[8];
    #pragma unroll
    for (int r = 0; r < 8; ++r) { z[r] = y[r] * qv[r]; sv[r] = qv[r] * kl; }
    #pragma unroll
    for (int m = 1; m < 64; m <<= 1) {
        #pragma unroll
        for (int r = 0; r < 8; ++r) {
            z[r]  += __shfl_xor(z[r],  m, 64);
            sv[r] += __shfl_xor(sv[r], m, 64);
        }
    }
    #pragma unroll
    for (int r = 0; r < 8; ++r) {
        if (lane == r) {
            float sum   = sv[r] * (1.0f / 32.0f);
            float sumsq = z[r]  * (1.0f / 1024.0f);
            float mu  = sum * (1.0f / 2048.0f);
            float var = (sumsq - sum * sum * (1.0f / 2048.0f)) * (1.0f / 2047.0f);
            var = fmaxf(var, 0.0f);
            float inv = 1.0f / (sqrtf(var) + 1e-8f);
            wsf[WS_A2 + q0 + r] = inv * (LOG2E / 32.0f);
            wsf[WS_C2 + q0 + r] = -mu * inv * LOG2E;
        }
    }
}

// ---------------------------------------------------------------------------
// 5) MFMA flash attention.  grid (ROWS/128, KSPLIT), block 256 (4 waves).
//    K/V loads are fragment-major -> contiguous 1KB wave loads from L2.
__global__ __launch_bounds__(256) void attention(float* __restrict__ wsf) {
    short* wsb = (short*)(wsf + WS_FEND);
    const short* Qb = wsb + WB_QB;
    const short* KF = wsb + WB_KF;
    const short* VF = wsb + WB_VF;
    __shared__ short P[4][32][72];   // per-wave [32 q][64 keys]

    const int t = threadIdx.x, w = t >> 6, lane = t & 63;
    const int l15 = lane & 15, g = lane >> 4;
    const int q0 = blockIdx.x * 128 + w * 32;
    const int b  = blockIdx.x >> 4;                 // 16 blocks per batch
    const int kb = blockIdx.y * (S_ / KSPLIT);      // 256-key range

    // preload Q B-frags (B[d][q]) and per-q exp2 coefficients
    bf16x8 bqf[2][2];
    float a2v[2], c2v[2];
    #pragma unroll
    for (int nt = 0; nt < 2; ++nt) {
        int q = q0 + nt*16 + l15;
        #pragma unroll
        for (int h = 0; h < 2; ++h)
            bqf[nt][h] = ldb(&Qb[(size_t)q * D_ + h*32 + g*8]);
        a2v[nt] = wsf[WS_A2 + q];
        c2v[nt] = wsf[WS_C2 + q];
    }

    floatx4 O[2][4] = {};
    float sacc[2] = {0.0f, 0.0f};
    short* Pw = &P[w][0][0];

    for (int kc = 0; kc < S_ / KSPLIT; kc += 64) {
        const int key0 = kb + kc;
        const int kblk16 = (b * S_ + key0) >> 4;
        const int kblk64 = (b * S_ + key0) >> 6;
        // --- S^T tiles: Sc[kt][nt], D[key][q] ---
        floatx4 Sc[4][2] = {};
        #pragma unroll
        for (int kt = 0; kt < 4; ++kt) {
            bf16x8 ak0 = ldb(&KF[(size_t)(((kblk16 + kt) * 2 + 0) * 64 + lane) * 8]);
            bf16x8 ak1 = ldb(&KF[(size_t)(((kblk16 + kt) * 2 + 1) * 64 + lane) * 8]);
            #pragma unroll
            for (int nt = 0; nt < 2; ++nt) {
                Sc[kt][nt] = MFMA(ak0, bqf[nt][0], Sc[kt][nt]);
                Sc[kt][nt] = MFMA(ak1, bqf[nt][1], Sc[kt][nt]);
            }
        }
        lds_fence();   // WAR: previous chunk's P reads must finish
        // --- exp2 + pack bf16 + write P[q][key] ---
        #pragma unroll
        for (int nt = 0; nt < 2; ++nt) {
            const float aa = a2v[nt], cc = c2v[nt];
            #pragma unroll
            for (int kt = 0; kt < 4; ++kt) {
                float w0 = exp2f(fmaf(Sc[kt][nt][0], aa, cc));
                float w1 = exp2f(fmaf(Sc[kt][nt][1], aa, cc));
                float w2 = exp2f(fmaf(Sc[kt][nt][2], aa, cc));
                float w3 = exp2f(fmaf(Sc[kt][nt][3], aa, cc));
                sacc[nt] += (w0 + w1) + (w2 + w3);
                short4 pk;
                pk.x = bfc(w0); pk.y = bfc(w1); pk.z = bfc(w2); pk.w = bfc(w3);
                *(short4*)&Pw[(nt*16 + l15) * 72 + kt*16 + 4*g] = pk;
            }
        }
        lds_fence();   // RAW: make P visible to all lanes of this wave
        // --- PV: O[q][d] += P.V ---
        bf16x8 ap[2][2];
        #pragma unroll
        for (int mt = 0; mt < 2; ++mt)
            #pragma unroll
            for (int kh = 0; kh < 2; ++kh)
                ap[mt][kh] = ldb(&Pw[(mt*16 + l15) * 72 + kh*32 + g*8]);
        #pragma unroll
        for (int nt = 0; nt < 4; ++nt) {
            #pragma unroll
            for (int kh = 0; kh < 2; ++kh) {
                bf16x8 bv = ldb(&VF[(size_t)(((kblk64 * 4 + nt) * 2 + kh) * 64 + lane) * 8]);
                #pragma unroll
                for (int mt = 0; mt < 2; ++mt)
                    O[mt][nt] = MFMA(ap[mt][kh], bv, O[mt][nt]);
            }
        }
    }

    // --- epilogue: reduce sumw over g-groups; store partials (no atomics) ---
    #pragma unroll
    for (int nt = 0; nt < 2; ++nt) {
        sacc[nt] += __shfl_xor(sacc[nt], 16, 64);
        sacc[nt] += __shfl_xor(sacc[nt], 32, 64);
    }
    if (lane < 16) {
        wsf[WS_SWP + blockIdx.y * ROWS + q0 + lane]      = sacc[0];
        wsf[WS_SWP + blockIdx.y * ROWS + q0 + 16 + lane] = sacc[1];
    }
    short* OP = wsb + WB_OP + ((size_t)blockIdx.y * ROWS + q0) * D_;
    #pragma unroll
    for (int mt = 0; mt < 2; ++mt)
        #pragma unroll
        for (int nt = 0; nt < 4; ++nt)
            #pragma unroll
            for (int r = 0; r < 4; ++r)
                OP[(size_t)(mt*16 + 4*g + r) * D_ + nt*16 + l15] =
                    (short)f2bf(O[mt][nt][r]);
}

// ---------------------------------------------------------------------------
// 6) reduce partials -> HNF (fragment-major) = (sum_p OP) / (sum_p SW).
__global__ __launch_bounds__(256) void reduceo(float* __restrict__ wsf) {
    short* wsb = (short*)(wsf + WS_FEND);
    const short* OP = wsb + WB_OP;
    short* HNF = wsb + WB_HNF;
    const int t = threadIdx.x;
    const int row = blockIdx.x * 32 + (t >> 3);
    const int c8 = (t & 7) * 8;
    float sw = 0.0f;
    #pragma unroll
    for (int p = 0; p < KSPLIT; ++p) sw += wsf[WS_SWP + p * ROWS + row];
    float inv = 1.0f / sw;
    float a[8] = {};
    #pragma unroll
    for (int p = 0; p < KSPLIT; ++p) {
        short8 o = *(const short8*)&OP[((size_t)p * ROWS + row) * D_ + c8];
        #pragma unroll
        for (int j = 0; j < 8; ++j) a[j] += bf2f(o[j]);
    }
    short8 hn;
    #pragma unroll
    for (int j = 0; j < 8; ++j) hn[j] = (short)f2bf(a[j] * inv);
    int kh = c8 >> 5, gH = (c8 >> 3) & 3;
    *(short8*)&HNF[(size_t)(((row >> 4) * 2 + kh) * 64 + gH * 16 + (row & 15)) * 8] = hn;
}

// ---------------------------------------------------------------------------
// 7) out = HN @ Weff + bout via MFMA (K=64), fragment-major loads.
//    grid (ROWS/64, H/64), block 256.
__global__ __launch_bounds__(256) void finalize(
    const float* __restrict__ bout, const float* __restrict__ wsf,
    float* __restrict__ out)
{
    const short* wsb = (const short*)(wsf + WS_FEND);
    const short* HNF = wsb + WB_HNF;
    const short* WFF = wsb + WB_WFF;
    const int t = threadIdx.x, w = t >> 6, lane = t & 63;
    const int l15 = lane & 15, g = lane >> 4;
    const int rowblk = blockIdx.x * 4 + w;      // 16-row tile
    const int r0 = rowblk * 16;
    const int c0 = blockIdx.y * 64;

    bf16x8 ah[2];
    #pragma unroll
    for (int h = 0; h < 2; ++h)
        ah[h] = ldb(&HNF[(size_t)((rowblk * 2 + h) * 64 + lane) * 8]);

    floatx4 acc[4] = {};
    #pragma unroll
    for (int nt = 0; nt < 4; ++nt) {
        #pragma unroll
        for (int h = 0; h < 2; ++h) {
            bf16x8 bf = ldb(&WFF[(size_t)((((c0 >> 4) + nt) * 2 + h) * 64 + lane) * 8]);
            acc[nt] = MFMA(ah[h], bf, acc[nt]);
        }
    }
    #pragma unroll
    for (int nt = 0; nt < 4; ++nt) {
        int col = c0 + nt*16 + l15;
        float bb = bout[col];
        #pragma unroll
        for (int r = 0; r < 4; ++r)
            out[(size_t)(r0 + 4*g + r) * H_ + col] = acc[nt][r] + bb;
    }
}

// ---------------------------------------------------------------------------
extern "C" void kernel_launch(void* const* d_in, const int* in_sizes, int n_in,
                              void* d_out, int out_size, void* d_ws, size_t ws_size,
                              hipStream_t stream) {
    const float* query = (const float*)d_in[0];
    const float* key   = (const float*)d_in[1];
    const float* value = (const float*)d_in[2];
    // d_in[3] mask / d_in[12] seq_mask: adding -1e-32 is a no-op in fp32 -> never read.
    const float* Wq   = (const float*)d_in[4];
    const float* bq   = (const float*)d_in[5];
    const float* Wk   = (const float*)d_in[6];
    const float* bk   = (const float*)d_in[7];
    const float* Wv   = (const float*)d_in[8];
    const float* bv   = (const float*)d_in[9];
    const float* Wout = (const float*)d_in[10];
    const float* bout = (const float*)d_in[11];

    float* ws  = (float*)d_ws;   // ~13.5 MB used
    float* out = (float*)d_out;

    prep<<<177, 256, 0, stream>>>(Wq, Wk, Wv, Wout, ws);
    qkv_mfma<<<dim3(ROWS/32, 3), 256, 0, stream>>>(query, key, value, bq, bk, bv, ws);
    kstats<<<B_ * 32, 256, 0, stream>>>(ws);
    rowstats<<<ROWS/32, 256, 0, stream>>>(ws);
    attention<<<dim3(ROWS/128, KSPLIT), 256, 0, stream>>>(ws);
    reduceo<<<ROWS/32, 256, 0, stream>>>(ws);
    finalize<<<dim3(ROWS/64, H_/64), 256, 0, stream>>>(bout, ws, out);
}